// Round 1
// baseline (1334.260 us; speedup 1.0000x reference)
//
#include <hip/hip_runtime.h>
#include <cstdint>
#include <cstddef>

#define NB 8
#define NPTS 8192
#define S_TOT 512
#define NSAMP 64
#define DFEAT 64
#define INCH 67

// exact (numpy-matching) squared distance: (a-b) per component, square, sum as (x+y)+z
__device__ __forceinline__ float d2_exact(float ax, float ay, float az,
                                          float bx, float by, float bz) {
    float dx = __fsub_rn(ax, bx);
    float dy = __fsub_rn(ay, by);
    float dz = __fsub_rn(az, bz);
    return __fadd_rn(__fadd_rn(__fmul_rn(dx, dx), __fmul_rn(dy, dy)), __fmul_rn(dz, dz));
}

// ---------------------------------------------------------------------------
// FPS: one block per (batch, group). group 0: attn_xyz, K=128, slots 0..127.
//      group 1: none_xyz, K=384, slots 128..511.
// 1024 threads, 8 points/thread held in registers. Emits new_xyz (out0) and
// new_attention (out2) directly.
// ---------------------------------------------------------------------------
__global__ __launch_bounds__(1024) void fps_kernel(
    const float* __restrict__ xyz,   // [B,3,N]
    const float* __restrict__ attn,  // [B,1,N]
    float* __restrict__ out0,        // [B,3,S]
    float* __restrict__ out2)        // [B,1,S]
{
    int blk = blockIdx.x;
    int b = blk >> 1;
    int grp = blk & 1;
    int K = grp ? 384 : 128;
    int soff = grp ? 128 : 0;
    int tid = threadIdx.x;
    int lane = tid & 63, wid = tid >> 6;

    const float* xb = xyz + (size_t)b * 3 * NPTS;
    const float* ab = attn + (size_t)b * NPTS;

    float px[8], py[8], pz[8], md[8];
#pragma unroll
    for (int i = 0; i < 8; i++) {
        int n = tid + i * 1024;
        float a = ab[n];
        float f = grp ? __fsub_rn(1.0f, a) : a;   // exact: a in {0,1}
        px[i] = __fmul_rn(f, xb[n]);
        py[i] = __fmul_rn(f, xb[NPTS + n]);
        pz[i] = __fmul_rn(f, xb[2 * NPTS + n]);
        md[i] = 1e10f;
    }

    __shared__ float s_bv[16], s_bx[16], s_by[16], s_bz[16];
    __shared__ int s_bi[16];
    __shared__ float s_lx, s_ly, s_lz;
    __shared__ int s_last;
    if (tid == 0) { s_last = 0; s_lx = px[0]; s_ly = py[0]; s_lz = pz[0]; }
    __syncthreads();

    for (int k = 0; k < K; k++) {
        int last = s_last;
        float lx = s_lx, ly = s_ly, lz = s_lz;
        if (tid == 0) {
            int sg = soff + k;
            out0[(size_t)b * 3 * S_TOT + sg] = lx;
            out0[(size_t)b * 3 * S_TOT + S_TOT + sg] = ly;
            out0[(size_t)b * 3 * S_TOT + 2 * S_TOT + sg] = lz;
            out2[(size_t)b * S_TOT + sg] = ab[last];
        }
        if (k == K - 1) break;

        // update min-dist and find local argmax (first-occurrence on ties)
        float bv = -1.0f; int bi = 0x7fffffff;
        float bx = 0.f, by = 0.f, bz = 0.f;
#pragma unroll
        for (int i = 0; i < 8; i++) {
            float d2 = d2_exact(px[i], py[i], pz[i], lx, ly, lz);
            md[i] = fminf(md[i], d2);
            if (md[i] > bv) { bv = md[i]; bi = tid + i * 1024; bx = px[i]; by = py[i]; bz = pz[i]; }
        }
        // wave reduce (prefer larger val; on tie smaller idx)
#pragma unroll
        for (int off = 32; off >= 1; off >>= 1) {
            float ov = __shfl_down(bv, off);
            int   oi = __shfl_down(bi, off);
            float ox = __shfl_down(bx, off);
            float oy = __shfl_down(by, off);
            float oz = __shfl_down(bz, off);
            if (ov > bv || (ov == bv && oi < bi)) { bv = ov; bi = oi; bx = ox; by = oy; bz = oz; }
        }
        if (lane == 0) { s_bv[wid] = bv; s_bi[wid] = bi; s_bx[wid] = bx; s_by[wid] = by; s_bz[wid] = bz; }
        __syncthreads();
        if (wid == 0) {
            // all 64 lanes active for well-defined shuffles; lanes >=16 carry losing sentinels
            bv = (lane < 16) ? s_bv[lane] : -2.0f;
            bi = (lane < 16) ? s_bi[lane] : 0x7fffffff;
            bx = (lane < 16) ? s_bx[lane] : 0.f;
            by = (lane < 16) ? s_by[lane] : 0.f;
            bz = (lane < 16) ? s_bz[lane] : 0.f;
#pragma unroll
            for (int off = 8; off >= 1; off >>= 1) {
                float ov = __shfl_down(bv, off);
                int   oi = __shfl_down(bi, off);
                float ox = __shfl_down(bx, off);
                float oy = __shfl_down(by, off);
                float oz = __shfl_down(bz, off);
                if (ov > bv || (ov == bv && oi < bi)) { bv = ov; bi = oi; bx = ox; by = oy; bz = oz; }
            }
            if (lane == 0) { s_last = bi; s_lx = bx; s_ly = by; s_lz = bz; }
        }
        __syncthreads();
    }
}

// ---------------------------------------------------------------------------
// points [B,64,N] -> ptsT [B,N,64], tiled 64x64 via LDS
// ---------------------------------------------------------------------------
__global__ void transpose_pts(const float* __restrict__ pts, float* __restrict__ ptsT) {
    __shared__ float t[64][65];
    int b = blockIdx.y;
    int n0 = blockIdx.x * 64;
    int tx = threadIdx.x, ty = threadIdx.y;
    for (int c = ty; c < 64; c += 4)
        t[c][tx] = pts[((size_t)b * DFEAT + c) * NPTS + n0 + tx];
    __syncthreads();
    for (int r = ty; r < 64; r += 4)
        ptsT[((size_t)b * NPTS + n0 + r) * DFEAT + tx] = t[tx][r];
}

// ---------------------------------------------------------------------------
// Ball query + feature build + 3-layer MLP + max over 64 samples.
// One wave (64 threads) per query; lane = sample slot.
// ---------------------------------------------------------------------------
__global__ __launch_bounds__(64) void ball_mlp(
    const float* __restrict__ xyz,    // [B,3,N]
    const float* __restrict__ pts,    // [B,64,N] (fallback gather)
    const float* __restrict__ ptsT,   // [B,N,64]
    int use_ptsT,
    const float* __restrict__ w0, const float* __restrict__ b0,
    const float* __restrict__ w1, const float* __restrict__ b1,
    const float* __restrict__ w2, const float* __restrict__ b2,
    const float* __restrict__ out0,   // queries = new_xyz [B,3,S]
    float* __restrict__ out1)         // [B,128,S]
{
    const float R2 = (float)(0.4 * 0.4);   // 0x3E23D70A — NOT 0.4f*0.4f
    int q = blockIdx.x;
    int b = q >> 9;
    int sg = q & 511;
    int lane = threadIdx.x;

    const float* xb = xyz + (size_t)b * 3 * NPTS;
    float qx = out0[(size_t)b * 3 * S_TOT + sg];
    float qy = out0[(size_t)b * 3 * S_TOT + S_TOT + sg];
    float qz = out0[(size_t)b * 3 * S_TOT + 2 * S_TOT + sg];

    __shared__ int s_idx[NSAMP];
    int cnt = 0;
    for (int base = 0; base < NPTS && cnt < NSAMP; base += 64) {
        int n = base + lane;
        float d2 = d2_exact(qx, qy, qz, xb[n], xb[NPTS + n], xb[2 * NPTS + n]);
        bool flag = d2 < R2;
        unsigned long long m = __ballot(flag);
        int pos = cnt + (int)__popcll(m & ((1ull << lane) - 1ull));
        if (flag && pos < NSAMP) s_idx[pos] = n;
        cnt += (int)__popcll(m);
    }
    __syncthreads();
    if (cnt > NSAMP) cnt = NSAMP;

    int nb = (lane < cnt) ? s_idx[lane] : -1;
    float nx_ = 0.f, ny_ = 0.f, nz_ = 0.f;
    if (nb >= 0) { nx_ = xb[nb]; ny_ = xb[NPTS + nb]; nz_ = xb[2 * NPTS + nb]; }
    float fx = nx_ - qx, fy = ny_ - qy, fz = nz_ - qz;   // pad: -new_xyz (ref semantics)
    int row = (nb < 0) ? (NPTS - 1) : nb;                // torch -1 wraps to last point

    // ---- layer 1: 67 -> 64 ----
    float h1[64];
#pragma unroll
    for (int o = 0; o < 64; o++) {
        float a = __builtin_fmaf(w0[o * INCH + 0], fx, b0[o]);
        a = __builtin_fmaf(w0[o * INCH + 1], fy, a);
        h1[o] = __builtin_fmaf(w0[o * INCH + 2], fz, a);
    }
    if (use_ptsT) {
        const float* prow = ptsT + ((size_t)b * NPTS + row) * DFEAT;
#pragma unroll 1
        for (int c = 0; c < 64; c += 4) {
            float4 f4 = *(const float4*)(prow + c);
#pragma unroll
            for (int o = 0; o < 64; o++) {
                float a = __builtin_fmaf(w0[o * INCH + 3 + c], f4.x, h1[o]);
                a = __builtin_fmaf(w0[o * INCH + 4 + c], f4.y, a);
                a = __builtin_fmaf(w0[o * INCH + 5 + c], f4.z, a);
                h1[o] = __builtin_fmaf(w0[o * INCH + 6 + c], f4.w, a);
            }
        }
    } else {
        const float* pb = pts + (size_t)b * DFEAT * NPTS + row;
#pragma unroll 1
        for (int c = 0; c < 64; c++) {
            float f = pb[(size_t)c * NPTS];
#pragma unroll
            for (int o = 0; o < 64; o++)
                h1[o] = __builtin_fmaf(w0[o * INCH + 3 + c], f, h1[o]);
        }
    }
#pragma unroll
    for (int o = 0; o < 64; o++) h1[o] = fmaxf(h1[o], 0.0f);

    // ---- layer 2: 64 -> 64 (fully unrolled: register-indexed h1/h2) ----
    float h2[64];
#pragma unroll
    for (int o = 0; o < 64; o++) h2[o] = b1[o];
#pragma unroll
    for (int c = 0; c < 64; c++) {
        float hc = h1[c];
#pragma unroll
        for (int o = 0; o < 64; o++)
            h2[o] = __builtin_fmaf(w1[o * 64 + c], hc, h2[o]);
    }
#pragma unroll
    for (int o = 0; o < 64; o++) h2[o] = fmaxf(h2[o], 0.0f);

    // ---- layer 3: 64 -> 128, relu, max over samples (lanes) ----
#pragma unroll 1
    for (int o = 0; o < 128; o++) {
        const float* wr = w2 + o * 64;
        float acc = b2[o];
#pragma unroll
        for (int c = 0; c < 64; c++) acc = __builtin_fmaf(wr[c], h2[c], acc);
        acc = fmaxf(acc, 0.0f);   // relu(max) == max(relu): monotone
#pragma unroll
        for (int off = 32; off >= 1; off >>= 1)
            acc = fmaxf(acc, __shfl_down(acc, off));
        if (lane == 0) out1[((size_t)(b * 128 + o)) * S_TOT + sg] = acc;
    }
}

extern "C" void kernel_launch(void* const* d_in, const int* in_sizes, int n_in,
                              void* d_out, int out_size, void* d_ws, size_t ws_size,
                              hipStream_t stream) {
    const float* xyz  = (const float*)d_in[0];
    const float* pts  = (const float*)d_in[1];
    const float* attn = (const float*)d_in[2];
    const float* w0 = (const float*)d_in[3];
    const float* b0 = (const float*)d_in[4];
    const float* w1 = (const float*)d_in[5];
    const float* b1 = (const float*)d_in[6];
    const float* w2 = (const float*)d_in[7];
    const float* b2 = (const float*)d_in[8];

    float* out0 = (float*)d_out;                    // [B,3,S]   = 12288
    float* out1 = out0 + (size_t)NB * 3 * S_TOT;    // [B,128,S] = 524288
    float* out2 = out1 + (size_t)NB * 128 * S_TOT;  // [B,1,S]   = 4096

    const size_t ptsT_bytes = (size_t)NB * NPTS * DFEAT * sizeof(float);  // 16.8 MB
    float* ptsT = (float*)d_ws;
    int use_ptsT = (ws_size >= ptsT_bytes) ? 1 : 0;

    if (use_ptsT)
        transpose_pts<<<dim3(NPTS / 64, NB), dim3(64, 4), 0, stream>>>(pts, ptsT);
    fps_kernel<<<16, 1024, 0, stream>>>(xyz, attn, out0, out2);
    ball_mlp<<<NB * S_TOT, 64, 0, stream>>>(xyz, pts, ptsT, use_ptsT,
                                            w0, b0, w1, b1, w2, b2, out0, out1);
}

// Round 2
// 960.907 us; speedup vs baseline: 1.3885x; 1.3885x over previous
//
#include <hip/hip_runtime.h>
#include <cstdint>
#include <cstddef>

#define NB 8
#define NPTS 8192
#define S_TOT 512
#define NSAMP 64
#define DFEAT 64
#define INCH 67

// exact (numpy-matching) squared distance: (a-b) per component, square, sum as (x+y)+z
__device__ __forceinline__ float d2_exact(float ax, float ay, float az,
                                          float bx, float by, float bz) {
    float dx = __fsub_rn(ax, bx);
    float dy = __fsub_rn(ay, by);
    float dz = __fsub_rn(az, bz);
    return __fadd_rn(__fadd_rn(__fmul_rn(dx, dx), __fmul_rn(dy, dy)), __fmul_rn(dz, dz));
}

// ---------------------------------------------------------------------------
// FPS: one block per (batch, group). group 0: attn, K=128, slots 0..127.
//      group 1: none, K=384, slots 128..511.
// 1024 threads, 8 points/thread in registers. ONE barrier per iteration:
// (min_d2, ~idx) packed in u64 (positive-float bits are order-monotone;
// ~idx => max picks smallest index on ties = numpy argmax first-occurrence),
// double-buffered 16-slot LDS reduce array, every wave redundantly does the
// final reduce, winner coords re-fetched by uniform (L2-resident) loads.
// ---------------------------------------------------------------------------
__global__ __launch_bounds__(1024, 1) void fps_kernel(
    const float* __restrict__ xyz,   // [B,3,N]
    const float* __restrict__ attn,  // [B,1,N]
    float* __restrict__ out0,        // [B,3,S]
    float* __restrict__ out2)        // [B,1,S]
{
    int blk = blockIdx.x;
    int b = blk >> 1;
    int grp = blk & 1;
    int K = grp ? 384 : 128;
    int soff = grp ? 128 : 0;
    int tid = threadIdx.x;
    int lane = tid & 63, wid = tid >> 6;

    const float* xb = xyz + (size_t)b * 3 * NPTS;
    const float* ab = attn + (size_t)b * NPTS;

    float px[8], py[8], pz[8], md[8];
#pragma unroll
    for (int i = 0; i < 8; i++) {
        int n = tid + i * 1024;
        float a = ab[n];
        float f = grp ? __fsub_rn(1.0f, a) : a;   // exact: a in {0,1}
        px[i] = __fmul_rn(f, xb[n]);
        py[i] = __fmul_rn(f, xb[NPTS + n]);
        pz[i] = __fmul_rn(f, xb[2 * NPTS + n]);
        md[i] = 1e10f;
    }

    __shared__ unsigned long long s_red[2][16];

    // current point = index 0
    float a_last = ab[0];
    float f0 = grp ? __fsub_rn(1.0f, a_last) : a_last;
    float lx = __fmul_rn(f0, xb[0]);
    float ly = __fmul_rn(f0, xb[NPTS]);
    float lz = __fmul_rn(f0, xb[2 * NPTS]);

    for (int k = 0; k < K; k++) {
        if (tid == 0) {
            int sg = soff + k;
            out0[(size_t)b * 3 * S_TOT + sg] = lx;
            out0[(size_t)b * 3 * S_TOT + S_TOT + sg] = ly;
            out0[(size_t)b * 3 * S_TOT + 2 * S_TOT + sg] = lz;
            out2[(size_t)b * S_TOT + sg] = a_last;
        }
        if (k == K - 1) break;

        // update min-dist, thread-local argmax (ascending local idx => strict '>'
        // keeps first occurrence)
        float bv = -1.0f; int bi = 0;
#pragma unroll
        for (int i = 0; i < 8; i++) {
            float d2 = d2_exact(px[i], py[i], pz[i], lx, ly, lz);
            md[i] = fminf(md[i], d2);
            if (md[i] > bv) { bv = md[i]; bi = tid + i * 1024; }
        }
        unsigned long long best =
            ((unsigned long long)__float_as_uint(bv) << 32) | (unsigned)(~bi);
#pragma unroll
        for (int off = 32; off >= 1; off >>= 1) {
            unsigned long long o = __shfl_down(best, off);
            best = (o > best) ? o : best;
        }
        if (lane == 0) s_red[k & 1][wid] = best;
        __syncthreads();

        // every wave redundantly reduces the 16 per-wave winners (no 2nd barrier;
        // s_red is double-buffered so next iteration's writes can't race)
        unsigned long long r = (lane < 16) ? s_red[k & 1][lane] : 0ull;
#pragma unroll
        for (int off = 8; off >= 1; off >>= 1) {
            unsigned long long o = __shfl_down(r, off);
            r = (o > r) ? o : r;
        }
        r = __shfl(r, 0);
        int n = (int)(~(unsigned)r);

        a_last = ab[n];                                   // uniform, L2-resident
        float fl = grp ? __fsub_rn(1.0f, a_last) : a_last;
        lx = __fmul_rn(fl, xb[n]);
        ly = __fmul_rn(fl, xb[NPTS + n]);
        lz = __fmul_rn(fl, xb[2 * NPTS + n]);
    }
}

// ---------------------------------------------------------------------------
// points [B,64,N] -> ptsT [B,N,64], tiled 64x64 via LDS
// ---------------------------------------------------------------------------
__global__ void transpose_pts(const float* __restrict__ pts, float* __restrict__ ptsT) {
    __shared__ float t[64][65];
    int b = blockIdx.y;
    int n0 = blockIdx.x * 64;
    int tx = threadIdx.x, ty = threadIdx.y;
    for (int c = ty; c < 64; c += 4)
        t[c][tx] = pts[((size_t)b * DFEAT + c) * NPTS + n0 + tx];
    __syncthreads();
    for (int r = ty; r < 64; r += 4)
        ptsT[((size_t)b * NPTS + n0 + r) * DFEAT + tx] = t[tx][r];
}

// w0 [64][67] -> w0T [67][64]; w1 [64][64] -> w1T [64][64] (both [in_ch][out_ch]:
// contiguous in o so the MLP's uniform weight reads merge into s_load_dwordx16)
__global__ void transpose_w(const float* __restrict__ w0, const float* __restrict__ w1,
                            float* __restrict__ w0T, float* __restrict__ w1T) {
    int t = blockIdx.x * 256 + threadIdx.x;
    if (t < INCH * 64) { int o = t & 63, c = t >> 6; w0T[c * 64 + o] = w0[o * INCH + c]; }
    if (t < 64 * 64)   { int o = t & 63, c = t >> 6; w1T[c * 64 + o] = w1[o * 64 + c]; }
}

// ---------------------------------------------------------------------------
// Ball query + feature build + 3-layer MLP + max over 64 samples.
// One wave per query; lane = sample slot. __launch_bounds__(64,2): cap VGPR
// at 256 so h1[64]+h2[64] stay in registers (R1's VGPR=92 meant spills ->
// 67MB scratch traffic). Occupancy >4 waves/SIMD is useless: total work is
// 4096 waves / 1024 SIMDs = 4 waves/SIMD.
// ---------------------------------------------------------------------------
__global__ __launch_bounds__(64, 2) void ball_mlp(
    const float* __restrict__ xyz,    // [B,3,N]
    const float* __restrict__ pts,    // [B,64,N] (fallback gather)
    const float* __restrict__ ptsT,   // [B,N,64]
    int use_ptsT,
    const float* __restrict__ w0T, const float* __restrict__ w1T, int use_wT,
    const float* __restrict__ w0, const float* __restrict__ b0,
    const float* __restrict__ w1, const float* __restrict__ b1,
    const float* __restrict__ w2, const float* __restrict__ b2,
    const float* __restrict__ out0,   // queries = new_xyz [B,3,S]
    float* __restrict__ out1)         // [B,128,S]
{
    const float R2 = (float)(0.4 * 0.4);   // 0x3E23D70A — NOT 0.4f*0.4f
    int q = blockIdx.x;
    int b = q >> 9;
    int sg = q & 511;
    int lane = threadIdx.x;

    const float* xb = xyz + (size_t)b * 3 * NPTS;
    float qx = out0[(size_t)b * 3 * S_TOT + sg];
    float qy = out0[(size_t)b * 3 * S_TOT + S_TOT + sg];
    float qz = out0[(size_t)b * 3 * S_TOT + 2 * S_TOT + sg];

    __shared__ int s_idx[NSAMP];
    int cnt = 0;
    for (int base = 0; base < NPTS && cnt < NSAMP; base += 64) {
        int n = base + lane;
        float d2 = d2_exact(qx, qy, qz, xb[n], xb[NPTS + n], xb[2 * NPTS + n]);
        bool flag = d2 < R2;
        unsigned long long m = __ballot(flag);
        int pos = cnt + (int)__popcll(m & ((1ull << lane) - 1ull));
        if (flag && pos < NSAMP) s_idx[pos] = n;
        cnt += (int)__popcll(m);
    }
    __syncthreads();
    if (cnt > NSAMP) cnt = NSAMP;

    int nb = (lane < cnt) ? s_idx[lane] : -1;
    float nx_ = 0.f, ny_ = 0.f, nz_ = 0.f;
    if (nb >= 0) { nx_ = xb[nb]; ny_ = xb[NPTS + nb]; nz_ = xb[2 * NPTS + nb]; }
    float fx = nx_ - qx, fy = ny_ - qy, fz = nz_ - qz;   // pad: -new_xyz (ref semantics)
    int row = (nb < 0) ? (NPTS - 1) : nb;                // torch -1 wraps to last point

    // ---- layer 1: 67 -> 64 ----
    float h1[64];
    if (use_wT) {
#pragma unroll
        for (int o = 0; o < 64; o++) {
            float a = __builtin_fmaf(w0T[o], fx, b0[o]);
            a = __builtin_fmaf(w0T[64 + o], fy, a);
            h1[o] = __builtin_fmaf(w0T[128 + o], fz, a);
        }
        if (use_ptsT) {
            const float* prow = ptsT + ((size_t)b * NPTS + row) * DFEAT;
#pragma unroll 1
            for (int c = 0; c < 64; c += 4) {
                float4 f4 = *(const float4*)(prow + c);
                const float* wr = w0T + (3 + c) * 64;
#pragma unroll
                for (int o = 0; o < 64; o++) {
                    float a = __builtin_fmaf(wr[o], f4.x, h1[o]);
                    a = __builtin_fmaf(wr[64 + o], f4.y, a);
                    a = __builtin_fmaf(wr[128 + o], f4.z, a);
                    h1[o] = __builtin_fmaf(wr[192 + o], f4.w, a);
                }
            }
        } else {
            const float* pb = pts + (size_t)b * DFEAT * NPTS + row;
#pragma unroll 1
            for (int c = 0; c < 64; c++) {
                float f = pb[(size_t)c * NPTS];
                const float* wr = w0T + (3 + c) * 64;
#pragma unroll
                for (int o = 0; o < 64; o++)
                    h1[o] = __builtin_fmaf(wr[o], f, h1[o]);
            }
        }
    } else {
#pragma unroll
        for (int o = 0; o < 64; o++) {
            float a = __builtin_fmaf(w0[o * INCH + 0], fx, b0[o]);
            a = __builtin_fmaf(w0[o * INCH + 1], fy, a);
            h1[o] = __builtin_fmaf(w0[o * INCH + 2], fz, a);
        }
        const float* pb = pts + (size_t)b * DFEAT * NPTS + row;
#pragma unroll 1
        for (int c = 0; c < 64; c++) {
            float f = use_ptsT ? ptsT[((size_t)b * NPTS + row) * DFEAT + c]
                               : pb[(size_t)c * NPTS];
#pragma unroll
            for (int o = 0; o < 64; o++)
                h1[o] = __builtin_fmaf(w0[o * INCH + 3 + c], f, h1[o]);
        }
    }
#pragma unroll
    for (int o = 0; o < 64; o++) h1[o] = fmaxf(h1[o], 0.0f);

    // ---- layer 2: 64 -> 64 (fully unrolled: register-indexed h1/h2) ----
    float h2[64];
#pragma unroll
    for (int o = 0; o < 64; o++) h2[o] = b1[o];
    if (use_wT) {
#pragma unroll
        for (int c = 0; c < 64; c++) {
            float hc = h1[c];
            const float* wr = w1T + c * 64;
#pragma unroll
            for (int o = 0; o < 64; o++)
                h2[o] = __builtin_fmaf(wr[o], hc, h2[o]);
        }
    } else {
#pragma unroll
        for (int c = 0; c < 64; c++) {
            float hc = h1[c];
#pragma unroll
            for (int o = 0; o < 64; o++)
                h2[o] = __builtin_fmaf(w1[o * 64 + c], hc, h2[o]);
        }
    }
#pragma unroll
    for (int o = 0; o < 64; o++) h2[o] = fmaxf(h2[o], 0.0f);

    // ---- layer 3: 64 -> 128 (w2 rows already contiguous), relu, lane-max ----
#pragma unroll 2
    for (int o = 0; o < 128; o++) {
        const float* wr = w2 + o * 64;
        float acc = b2[o];
#pragma unroll
        for (int c = 0; c < 64; c++) acc = __builtin_fmaf(wr[c], h2[c], acc);
        acc = fmaxf(acc, 0.0f);   // relu(max) == max(relu): monotone
#pragma unroll
        for (int off = 32; off >= 1; off >>= 1)
            acc = fmaxf(acc, __shfl_down(acc, off));
        if (lane == 0) out1[((size_t)(b * 128 + o)) * S_TOT + sg] = acc;
    }
}

extern "C" void kernel_launch(void* const* d_in, const int* in_sizes, int n_in,
                              void* d_out, int out_size, void* d_ws, size_t ws_size,
                              hipStream_t stream) {
    const float* xyz  = (const float*)d_in[0];
    const float* pts  = (const float*)d_in[1];
    const float* attn = (const float*)d_in[2];
    const float* w0 = (const float*)d_in[3];
    const float* b0 = (const float*)d_in[4];
    const float* w1 = (const float*)d_in[5];
    const float* b1 = (const float*)d_in[6];
    const float* w2 = (const float*)d_in[7];
    const float* b2 = (const float*)d_in[8];

    float* out0 = (float*)d_out;                    // [B,3,S]   = 12288
    float* out1 = out0 + (size_t)NB * 3 * S_TOT;    // [B,128,S] = 524288
    float* out2 = out1 + (size_t)NB * 128 * S_TOT;  // [B,1,S]   = 4096

    // ws layout: w0T (4288 f) | w1T (4096 f) | pad to 8448 f | ptsT (16.8 MB)
    float* w0T  = (float*)d_ws;
    float* w1T  = w0T + INCH * 64;
    float* ptsT = w0T + 8448;
    const size_t wT_bytes   = 8448 * sizeof(float);
    const size_t ptsT_bytes = (size_t)NB * NPTS * DFEAT * sizeof(float);
    int use_wT   = (ws_size >= wT_bytes) ? 1 : 0;
    int use_ptsT = (ws_size >= wT_bytes + ptsT_bytes) ? 1 : 0;

    if (use_wT)
        transpose_w<<<(INCH * 64 + 255) / 256, 256, 0, stream>>>(w0, w1, w0T, w1T);
    if (use_ptsT)
        transpose_pts<<<dim3(NPTS / 64, NB), dim3(64, 4), 0, stream>>>(pts, ptsT);
    fps_kernel<<<16, 1024, 0, stream>>>(xyz, attn, out0, out2);
    ball_mlp<<<NB * S_TOT, 64, 0, stream>>>(xyz, pts, ptsT, use_ptsT,
                                            w0T, w1T, use_wT,
                                            w0, b0, w1, b1, w2, b2, out0, out1);
}